// Round 2
// baseline (471.065 us; speedup 1.0000x reference)
//
#include <hip/hip_runtime.h>
#include <stdint.h>

#define Bn 64
#define Tn 512
#define Dn 1024
#define Ln 32
#define LOG2E 1.4426950408889634f
#define LN2f  0.6931471805599453f

// workspace float offsets
#define EMIS_OFF 0
#define LOGNORM_OFF (Bn * Tn * Ln)          // 1048576
#define SCORE_OFF (LOGNORM_OFF + Bn)
#define CNT_OFF (SCORE_OFF + Bn)            // 3*Bn floats (tp, tn, fp per batch)

// macro-expanded constant-immediate swizzle broadcasts
#define SWZB(vi, i) __builtin_amdgcn_ds_swizzle((vi), 0x10 | ((i) << 5))
#define DO16(F) F(0) F(1) F(2) F(3) F(4) F(5) F(6) F(7) \
                F(8) F(9) F(10) F(11) F(12) F(13) F(14) F(15)

// ---------------------------------------------------------------------------
// Kernel 1: emissions = x @ W + bias   (f32, vector ALU — no f32 MFMA on CDNA4)
// grid: Bn * (Tn/128) = 256 blocks, 256 threads. Skips tiles with t0 >= seqlen.
// ---------------------------------------------------------------------------
#define BM 128
#define KB 32
#define XSS (BM + 4)    // LDS stride

__global__ __launch_bounds__(256) void gemm_emis(
    const float* __restrict__ x, const float* __restrict__ Wm,
    const float* __restrict__ bias, const int* __restrict__ seqlen,
    float* __restrict__ emis)
{
    int b  = blockIdx.x >> 2;
    int t0 = (blockIdx.x & 3) * BM;
    if (t0 >= seqlen[b]) return;   // emissions for t >= seqlen are never read

    __shared__ float xs[KB * XSS];     // x tile, transposed: xs[k][row]
    __shared__ float wsh[KB * Ln];     // W tile: wsh[k][col]

    int tid = threadIdx.x;
    int cg = tid & 7;       // col group: cols 4cg..4cg+3
    int rr = tid >> 3;      // row group: rows 4rr..4rr+3

    float acc[4][4];
    #pragma unroll
    for (int i = 0; i < 4; i++)
        #pragma unroll
        for (int jj = 0; jj < 4; jj++) acc[i][jj] = 0.f;

    const float* xrow = x + (size_t)(b * Tn + t0) * Dn;

    for (int k0 = 0; k0 < Dn; k0 += KB) {
        // stage W chunk: 32 k-rows x 32 cols = 1024 floats, contiguous
        {
            float4 wv = *(const float4*)(Wm + (size_t)k0 * Ln + tid * 4);
            *(float4*)(wsh + tid * 4) = wv;
        }
        // stage x chunk: 128 rows x 32 k = 1024 float4s, transposed into LDS
        #pragma unroll
        for (int u = 0; u < 4; u++) {
            int f4 = tid + 256 * u;
            int lrow = f4 >> 3;          // 0..127
            int kk = f4 & 7;             // 0..7 (float4 within k-chunk)
            float4 xv = *(const float4*)(xrow + (size_t)lrow * Dn + k0 + kk * 4);
            xs[(4 * kk + 0) * XSS + lrow] = xv.x;
            xs[(4 * kk + 1) * XSS + lrow] = xv.y;
            xs[(4 * kk + 2) * XSS + lrow] = xv.z;
            xs[(4 * kk + 3) * XSS + lrow] = xv.w;
        }
        __syncthreads();
        #pragma unroll 8
        for (int k = 0; k < KB; k++) {
            float4 a = *(const float4*)(xs + k * XSS + 4 * rr);
            float4 w = *(const float4*)(wsh + k * Ln + 4 * cg);
            float av[4] = {a.x, a.y, a.z, a.w};
            float wv[4] = {w.x, w.y, w.z, w.w};
            #pragma unroll
            for (int z = 0; z < 4; z++)
                #pragma unroll
                for (int c = 0; c < 4; c++)
                    acc[z][c] = fmaf(av[z], wv[c], acc[z][c]);
        }
        __syncthreads();
    }

    float4 bv = *(const float4*)(bias + 4 * cg);
    float bb[4] = {bv.x, bv.y, bv.z, bv.w};
    #pragma unroll
    for (int z = 0; z < 4; z++) {
        float4 o;
        o.x = acc[z][0] + bb[0];
        o.y = acc[z][1] + bb[1];
        o.z = acc[z][2] + bb[2];
        o.w = acc[z][3] + bb[3];
        *(float4*)(emis + (size_t)(b * Tn + t0 + 4 * rr + z) * Ln + 4 * cg) = o;
    }
}

// ---------------------------------------------------------------------------
// Kernel 2: per-batch CRF forward (LSE + Viterbi + seq-score) and backtrace.
// grid: 64 blocks x 512 threads.
//   wave0 = Viterbi forward (bp -> LDS), wave1 = log-norm forward,
//   wave2 = sequence score; then all 512 threads do the parallel backtrace.
// Lane mapping for forward waves (wave64 = two 32-lane groups; within each
// group, group-lane p holds alpha[p]): h = (L>>4)&1 selects the i-half this
// lane's trans rows cover; j = (L&15) + 16*(L>>5) is the output tag.
// Broadcast alpha[16h+i] via ds_swizzle imm (and=0x10, or=i).
// ---------------------------------------------------------------------------
__global__ __launch_bounds__(512) void crf_forward(
    const float* __restrict__ emis, const float* __restrict__ trans,
    const int* __restrict__ label, const int* __restrict__ seqlen,
    float* __restrict__ out, float* __restrict__ wsf)
{
    __shared__ uint8_t bp[Tn * Ln];     // backpointers, 16 KB
    __shared__ uint8_t Fm[16 * 32];     // segment maps
    __shared__ int btag[16];
    __shared__ int s_last;
    __shared__ float credA[8], credB[8], credC[8];

    int tid = threadIdx.x;
    int b = blockIdx.x;
    int slen = seqlen[b];
    int wv = tid >> 6;
    int lane = tid & 63;

    // init backpointers to identity (covers t >= slen and t == 0)
    for (int idx = tid; idx < Tn * Ln; idx += 512) bp[idx] = (uint8_t)(idx & 31);
    __syncthreads();

    const float* eb = emis + (size_t)b * Tn * Ln;

    if (wv == 0) {
        // ---------------- Viterbi forward ----------------
        int h = (lane >> 4) & 1;
        int j = (lane & 15) + ((lane >> 5) << 4);
        int vidx = (lane & 15) + (h << 4);
        int swapsrc = (lane >= 16 && lane < 48) ? (lane ^ 48) : lane;
        int swapaddr = swapsrc << 2;

        float tr[16];
        #pragma unroll
        for (int i = 0; i < 16; i++) tr[i] = trans[(16 * h + i) * Ln + j];

        float av = eb[vidx];
        float emit = eb[Ln + j];   // t=1 preload (unused if slen==1)

        for (int t = 1; t < slen; t++) {
            int tnx = (t + 1 < slen) ? (t + 1) : (slen - 1);
            float emitn = eb[(size_t)tnx * Ln + j];

            int avi = __float_as_int(av);
            float vv[16];
            #define VSTEP(i) vv[i] = __int_as_float(SWZB(avi, i)) + tr[i];
            DO16(VSTEP)
            #undef VSTEP
            // depth-4 argmax tree, first-index-wins (pairs ascend)
            float mv[8]; int mi[8];
            #pragma unroll
            for (int i = 0; i < 8; i++) {
                bool g = vv[2 * i + 1] > vv[2 * i];
                mv[i] = g ? vv[2 * i + 1] : vv[2 * i];
                mi[i] = g ? (2 * i + 1) : (2 * i);
            }
            #pragma unroll
            for (int i = 0; i < 4; i++) {
                bool g = mv[2 * i + 1] > mv[2 * i];
                mv[i] = g ? mv[2 * i + 1] : mv[2 * i];
                mi[i] = g ? mi[2 * i + 1] : mi[2 * i];
            }
            #pragma unroll
            for (int i = 0; i < 2; i++) {
                bool g = mv[2 * i + 1] > mv[2 * i];
                mv[i] = g ? mv[2 * i + 1] : mv[2 * i];
                mi[i] = g ? mi[2 * i + 1] : mi[2 * i];
            }
            bool g0 = mv[1] > mv[0];
            float m = g0 ? mv[1] : mv[0];
            int am = 16 * h + (g0 ? mi[1] : mi[0]);

            float mp  = __int_as_float(__builtin_amdgcn_ds_swizzle(__float_as_int(m), 0x401F));
            int   amp = __builtin_amdgcn_ds_swizzle(am, 0x401F);
            float mlo = h ? mp : m;  int alo = h ? amp : am;
            float mhi = h ? m  : mp; int ahi = h ? am  : amp;
            int bpi = (mhi > mlo) ? ahi : alo;           // tie -> low half (first idx)
            float best = ((mhi > mlo) ? mhi : mlo) + emit;
            if (h == 0) bp[t * Ln + j] = (uint8_t)bpi;
            av = __int_as_float(__builtin_amdgcn_ds_bpermute(swapaddr, __float_as_int(best)));
            emit = emitn;
        }
        // last = argmax(alpha), first-index tie-break (duplicates are identical)
        float mm = av; int ai = vidx;
        #pragma unroll
        for (int off = 16; off >= 1; off >>= 1) {
            float om = __shfl_xor(mm, off);
            int   oi = __shfl_xor(ai, off);
            if (om > mm || (om == mm && oi < ai)) { mm = om; ai = oi; }
        }
        int o32 = __shfl_xor(ai, 32);
        float ov32 = __shfl_xor(mm, 32);
        if (ov32 > mm || (ov32 == mm && o32 < ai)) { ai = o32; }
        if (lane == 0) s_last = ai;
    } else if (wv == 1) {
        // ---------------- log-norm forward (LSE) ----------------
        int h = (lane >> 4) & 1;
        int j = (lane & 15) + ((lane >> 5) << 4);
        int vidx = (lane & 15) + (h << 4);
        int swapsrc = (lane >= 16 && lane < 48) ? (lane ^ 48) : lane;
        int swapaddr = swapsrc << 2;

        float e2[16];
        #pragma unroll
        for (int i = 0; i < 16; i++)
            e2[i] = exp2f(trans[(16 * h + i) * Ln + j] * LOG2E);  // exp(T_ij)

        float al = eb[vidx];
        float emit = eb[Ln + j];

        for (int t = 1; t < slen; t++) {
            int tnx = (t + 1 < slen) ? (t + 1) : (slen - 1);
            float emitn = eb[(size_t)tnx * Ln + j];

            float M = __int_as_float(__builtin_amdgcn_readfirstlane(__float_as_int(al)));
            float w = exp2f((al - M) * LOG2E);
            int wi = __float_as_int(w);
            float s0 = 0.f, s1 = 0.f, s2 = 0.f, s3 = 0.f;
            #define LSTEP(i) { float wb = __int_as_float(SWZB(wi, i)); \
                               if ((i & 3) == 0) s0 = fmaf(wb, e2[i], s0); \
                               else if ((i & 3) == 1) s1 = fmaf(wb, e2[i], s1); \
                               else if ((i & 3) == 2) s2 = fmaf(wb, e2[i], s2); \
                               else s3 = fmaf(wb, e2[i], s3); }
            DO16(LSTEP)
            #undef LSTEP
            float s = (s0 + s1) + (s2 + s3);
            s += __int_as_float(__builtin_amdgcn_ds_swizzle(__float_as_int(s), 0x401F));
            float anew = fmaf(log2f(s), LN2f, M) + emit;
            al = __int_as_float(__builtin_amdgcn_ds_bpermute(swapaddr, __float_as_int(anew)));
            emit = emitn;
        }
        // final logsumexp; each alpha appears twice across 64 lanes -> 0.5x
        float mm = al;
        #pragma unroll
        for (int off = 32; off >= 1; off >>= 1) mm = fmaxf(mm, __shfl_xor(mm, off));
        float ee = exp2f((al - mm) * LOG2E);
        #pragma unroll
        for (int off = 32; off >= 1; off >>= 1) ee += __shfl_xor(ee, off);
        if (lane == 0) wsf[LOGNORM_OFF + b] = fmaf(log2f(0.5f * ee), LN2f, mm);
    } else if (wv == 2) {
        // ---------------- sequence score ----------------
        const int* lb = label + (size_t)b * Tn;
        float acc = 0.f;
        for (int t = lane; t < Tn; t += 64) {
            if (t < slen) {
                int lc = lb[t];
                acc += eb[(size_t)t * Ln + lc];
                if (t >= 1) acc += trans[lb[t - 1] * Ln + lc];
            }
        }
        #pragma unroll
        for (int off = 32; off >= 1; off >>= 1) acc += __shfl_xor(acc, off);
        if (lane == 0) wsf[SCORE_OFF + b] = acc;
    }
    __syncthreads();

    // ---------------- parallel backtrace ----------------
    // phase 1: per-segment composed maps F_s(e), 16 segments x 32 entries
    int sseg = tid >> 5, ent = tid & 31;
    {
        int y = ent;
        for (int p = 32 * sseg + 31; p >= 32 * sseg; p--) y = bp[p * Ln + y];
        Fm[sseg * 32 + ent] = (uint8_t)y;
    }
    __syncthreads();
    // phase 2: boundary tags B_s (tag at position 32s+31)
    if (tid == 0) {
        int y = s_last;
        btag[15] = y;
        for (int ss = 15; ss >= 1; ss--) { y = Fm[ss * 32 + y]; btag[ss - 1] = y; }
    }
    __syncthreads();
    // phase 3: interior tags; thread tid handles position q = tid
    int q = tid;
    int y = btag[sseg];
    for (int p = 32 * sseg + 31; p >= q + 1; p--) y = bp[p * Ln + y];
    out[1 + (size_t)b * Tn + q] = (float)y;

    int lbl = label[(size_t)b * Tn + q];
    float tpf = (lbl > 0 && y == lbl) ? 1.f : 0.f;
    float tnf = (lbl > 0 && y != lbl) ? 1.f : 0.f;
    float fpf = (q < slen && lbl == 0 && y > 0) ? 1.f : 0.f;
    #pragma unroll
    for (int off = 32; off >= 1; off >>= 1) {
        tpf += __shfl_xor(tpf, off);
        tnf += __shfl_xor(tnf, off);
        fpf += __shfl_xor(fpf, off);
    }
    if (lane == 0) { credA[wv] = tpf; credB[wv] = tnf; credC[wv] = fpf; }
    __syncthreads();
    if (tid == 0) {
        float a = 0.f, bb2 = 0.f, c = 0.f;
        #pragma unroll
        for (int w = 0; w < 8; w++) { a += credA[w]; bb2 += credB[w]; c += credC[w]; }
        wsf[CNT_OFF + b] = a;
        wsf[CNT_OFF + Bn + b] = bb2;
        wsf[CNT_OFF + 2 * Bn + b] = c;
    }
}

// ---------------------------------------------------------------------------
// Kernel 3: final scalar reductions
// ---------------------------------------------------------------------------
__global__ __launch_bounds__(64) void crf_final(const float* __restrict__ wsf,
                                                float* __restrict__ out)
{
    int lane = threadIdx.x;
    float nll = wsf[LOGNORM_OFF + lane] - wsf[SCORE_OFF + lane];
    float tp = wsf[CNT_OFF + lane];
    float tn = wsf[CNT_OFF + Bn + lane];
    float fp = wsf[CNT_OFF + 2 * Bn + lane];
    #pragma unroll
    for (int off = 32; off >= 1; off >>= 1) {
        nll += __shfl_xor(nll, off);
        tp  += __shfl_xor(tp, off);
        tn  += __shfl_xor(tn, off);
        fp  += __shfl_xor(fp, off);
    }
    if (lane == 0) {
        out[0] = nll * (1.f / 64.f);
        out[1 + Bn * Tn + 0] = tp;
        out[1 + Bn * Tn + 1] = tn;
        out[1 + Bn * Tn + 2] = fp;
    }
}

extern "C" void kernel_launch(void* const* d_in, const int* in_sizes, int n_in,
                              void* d_out, int out_size, void* d_ws, size_t ws_size,
                              hipStream_t stream) {
    const float* x     = (const float*)d_in[0];
    const float* W     = (const float*)d_in[1];
    const float* bias  = (const float*)d_in[2];
    const float* trans = (const float*)d_in[3];
    const int* label   = (const int*)d_in[4];
    const int* seqlen  = (const int*)d_in[5];
    float* out = (float*)d_out;
    float* wsf = (float*)d_ws;

    gemm_emis<<<dim3(Bn * (Tn / BM)), dim3(256), 0, stream>>>(x, W, bias, seqlen, wsf + EMIS_OFF);
    crf_forward<<<dim3(Bn), dim3(512), 0, stream>>>(wsf + EMIS_OFF, trans, label, seqlen, out, wsf);
    crf_final<<<dim3(1), dim3(64), 0, stream>>>(wsf, out);
}

// Round 3
// 358.429 us; speedup vs baseline: 1.3142x; 1.3142x over previous
//
#include <hip/hip_runtime.h>
#include <stdint.h>

#define Bn 64
#define Tn 512
#define Dn 1024
#define Ln 32
#define LOG2E 1.4426950408889634f
#define LN2f  0.6931471805599453f

// workspace float offsets
#define EMIS_OFF 0
#define LOGNORM_OFF (Bn * Tn * Ln)          // 1048576
#define SCORE_OFF (LOGNORM_OFF + Bn)
#define CNT_OFF (SCORE_OFF + Bn)            // 3*Bn floats (tp, tn, fp per batch)

#define DO32(F) F(0) F(1) F(2) F(3) F(4) F(5) F(6) F(7) \
                F(8) F(9) F(10) F(11) F(12) F(13) F(14) F(15) \
                F(16) F(17) F(18) F(19) F(20) F(21) F(22) F(23) \
                F(24) F(25) F(26) F(27) F(28) F(29) F(30) F(31)

// ---------------------------------------------------------------------------
// Kernel 1: emissions = x @ W + bias   (f32, vector ALU — no f32 MFMA on CDNA4)
// grid: Bn * (Tn/128) = 256 blocks, 256 threads. Skips tiles with t0 >= seqlen.
// (unchanged from R2 — measured-good enough; crf was the 48% dispatch)
// ---------------------------------------------------------------------------
#define BM 128
#define KB 32
#define XSS (BM + 4)    // LDS stride; *4B stays 16B-aligned for b128 reads

__global__ __launch_bounds__(256) void gemm_emis(
    const float* __restrict__ x, const float* __restrict__ Wm,
    const float* __restrict__ bias, const int* __restrict__ seqlen,
    float* __restrict__ emis)
{
    int b  = blockIdx.x >> 2;
    int t0 = (blockIdx.x & 3) * BM;
    if (t0 >= seqlen[b]) return;   // emissions for t >= seqlen are never read

    __shared__ float xs[KB * XSS];     // x tile, transposed: xs[k][row]
    __shared__ float wsh[KB * Ln];     // W tile: wsh[k][col]

    int tid = threadIdx.x;
    int cg = tid & 7;       // col group: cols 4cg..4cg+3
    int rr = tid >> 3;      // row group: rows 4rr..4rr+3

    float acc[4][4];
    #pragma unroll
    for (int i = 0; i < 4; i++)
        #pragma unroll
        for (int jj = 0; jj < 4; jj++) acc[i][jj] = 0.f;

    const float* xrow = x + (size_t)(b * Tn + t0) * Dn;

    for (int k0 = 0; k0 < Dn; k0 += KB) {
        {
            float4 wv = *(const float4*)(Wm + (size_t)k0 * Ln + tid * 4);
            *(float4*)(wsh + tid * 4) = wv;
        }
        #pragma unroll
        for (int u = 0; u < 4; u++) {
            int f4 = tid + 256 * u;
            int lrow = f4 >> 3;          // 0..127
            int kk = f4 & 7;             // 0..7
            float4 xv = *(const float4*)(xrow + (size_t)lrow * Dn + k0 + kk * 4);
            xs[(4 * kk + 0) * XSS + lrow] = xv.x;
            xs[(4 * kk + 1) * XSS + lrow] = xv.y;
            xs[(4 * kk + 2) * XSS + lrow] = xv.z;
            xs[(4 * kk + 3) * XSS + lrow] = xv.w;
        }
        __syncthreads();
        #pragma unroll 8
        for (int k = 0; k < KB; k++) {
            float4 a = *(const float4*)(xs + k * XSS + 4 * rr);
            float4 w = *(const float4*)(wsh + k * Ln + 4 * cg);
            float av[4] = {a.x, a.y, a.z, a.w};
            float wv[4] = {w.x, w.y, w.z, w.w};
            #pragma unroll
            for (int z = 0; z < 4; z++)
                #pragma unroll
                for (int c = 0; c < 4; c++)
                    acc[z][c] = fmaf(av[z], wv[c], acc[z][c]);
        }
        __syncthreads();
    }

    float4 bv = *(const float4*)(bias + 4 * cg);
    float bb[4] = {bv.x, bv.y, bv.z, bv.w};
    #pragma unroll
    for (int z = 0; z < 4; z++) {
        float4 o;
        o.x = acc[z][0] + bb[0];
        o.y = acc[z][1] + bb[1];
        o.z = acc[z][2] + bb[2];
        o.w = acc[z][3] + bb[3];
        *(float4*)(emis + (size_t)(b * Tn + t0 + 4 * rr + z) * Ln + 4 * cg) = o;
    }
}

// ---------------------------------------------------------------------------
// Kernel 2: per-batch CRF forward + backtrace. grid 64 x 512.
// wave0 = Viterbi, wave1 = log-norm, wave2 = seq score; waves 3-7 help stage.
// Recurrence layout: lane holds state j = lane&31 (halves replicated).
// Cross-lane broadcast via v_readlane -> SGPR (no LDS round trip in chain).
// Emissions staged to LDS up-front (no vmcnt in the serial loop).
// ---------------------------------------------------------------------------
__global__ __launch_bounds__(512) void crf_forward(
    const float* __restrict__ emis, const float* __restrict__ trans,
    const int* __restrict__ label, const int* __restrict__ seqlen,
    float* __restrict__ out, float* __restrict__ wsf)
{
    __shared__ __align__(16) float es[Tn * Ln];   // 64 KB staged emissions
    __shared__ uint8_t bp[Tn * Ln];               // 16 KB backpointers
    __shared__ uint8_t Fm[16 * 32];
    __shared__ int btag[16];
    __shared__ int s_last;
    __shared__ float credA[8], credB[8], credC[8];

    int tid = threadIdx.x;
    int b = blockIdx.x;
    int slen = seqlen[b];
    int wv = tid >> 6;
    int lane = tid & 63;

    const float* eb = emis + (size_t)b * Tn * Ln;

    // stage emissions (only rows < slen are ever read) — coalesced float4
    {
        int n4 = slen * (Ln / 4);
        for (int i4 = tid; i4 < n4; i4 += 512)
            ((float4*)es)[i4] = ((const float4*)eb)[i4];
    }
    // init backpointers to identity via u32 words
    {
        uint32_t* bp32 = (uint32_t*)bp;
        for (int w = tid; w < Tn * Ln / 4; w += 512)
            bp32[w] = 0x03020100u + 0x04040404u * (uint32_t)(w & 7);
    }
    __syncthreads();

    if (wv == 0) {
        // ---------------- Viterbi forward (exact, first-index ties) --------
        int j = lane & 31;
        float tr[32];
        #pragma unroll
        for (int i = 0; i < 32; i++) tr[i] = trans[i * Ln + j];

        float av = es[j];
        float emit = es[Ln + j];   // t=1 preload (unused if slen==1)

        for (int t = 1; t < slen; t++) {
            int tnx = (t + 1 < slen) ? (t + 1) : (slen - 1);
            float emitn = es[tnx * Ln + j];

            int avi = __float_as_int(av);
            float vv[32];
            #define VSTEP(i) vv[i] = __int_as_float(__builtin_amdgcn_readlane(avi, i)) + tr[i];
            DO32(VSTEP)
            #undef VSTEP
            // exact first-index argmax tree (pairs ascend; strict > keeps lo)
            float mv[16]; int mi[16];
            #pragma unroll
            for (int i = 0; i < 16; i++) {
                bool g = vv[2 * i + 1] > vv[2 * i];
                mv[i] = g ? vv[2 * i + 1] : vv[2 * i];
                mi[i] = g ? (2 * i + 1) : (2 * i);
            }
            #pragma unroll
            for (int i = 0; i < 8; i++) {
                bool g = mv[2 * i + 1] > mv[2 * i];
                mv[i] = g ? mv[2 * i + 1] : mv[2 * i];
                mi[i] = g ? mi[2 * i + 1] : mi[2 * i];
            }
            #pragma unroll
            for (int i = 0; i < 4; i++) {
                bool g = mv[2 * i + 1] > mv[2 * i];
                mv[i] = g ? mv[2 * i + 1] : mv[2 * i];
                mi[i] = g ? mi[2 * i + 1] : mi[2 * i];
            }
            #pragma unroll
            for (int i = 0; i < 2; i++) {
                bool g = mv[2 * i + 1] > mv[2 * i];
                mv[i] = g ? mv[2 * i + 1] : mv[2 * i];
                mi[i] = g ? mi[2 * i + 1] : mi[2 * i];
            }
            if (lane < 32) bp[t * Ln + j] = (uint8_t)mi[0];
            av = mv[0] + emit;
            emit = emitn;
        }
        // argmax over 32 states (lanes 0..31 distinct; halves identical)
        float mm = av; int ai = j;
        #pragma unroll
        for (int off = 16; off >= 1; off >>= 1) {
            float om = __shfl_xor(mm, off);
            int   oi = __shfl_xor(ai, off);
            if (om > mm || (om == mm && oi < ai)) { mm = om; ai = oi; }
        }
        if (lane == 0) s_last = ai;
    } else if (wv == 1) {
        // ---------------- log-norm forward (LSE, readlane broadcasts) ------
        int j = lane & 31;
        float e2[32];
        #pragma unroll
        for (int i = 0; i < 32; i++)
            e2[i] = exp2f(trans[i * Ln + j] * LOG2E);   // exp(T_ij)

        float al = es[j];
        float emit = es[Ln + j];

        for (int t = 1; t < slen; t++) {
            int tnx = (t + 1 < slen) ? (t + 1) : (slen - 1);
            float emitn = es[tnx * Ln + j];

            float M = __int_as_float(__builtin_amdgcn_readfirstlane(__float_as_int(al)));
            float w = exp2f((al - M) * LOG2E);
            int wi = __float_as_int(w);
            float s0 = 0.f, s1 = 0.f, s2 = 0.f, s3 = 0.f;
            #define LSTEP(i) { float wb = __int_as_float(__builtin_amdgcn_readlane(wi, i)); \
                               if ((i & 3) == 0) s0 = fmaf(wb, e2[i], s0); \
                               else if ((i & 3) == 1) s1 = fmaf(wb, e2[i], s1); \
                               else if ((i & 3) == 2) s2 = fmaf(wb, e2[i], s2); \
                               else s3 = fmaf(wb, e2[i], s3); }
            DO32(LSTEP)
            #undef LSTEP
            float s = (s0 + s1) + (s2 + s3);
            al = fmaf(log2f(s), LN2f, M) + emit;
            emit = emitn;
        }
        // final logsumexp over 32 states (xor 16..1 stays within halves)
        float mm = al;
        #pragma unroll
        for (int off = 16; off >= 1; off >>= 1) mm = fmaxf(mm, __shfl_xor(mm, off));
        float ee = exp2f((al - mm) * LOG2E);
        #pragma unroll
        for (int off = 16; off >= 1; off >>= 1) ee += __shfl_xor(ee, off);
        if (lane == 0) wsf[LOGNORM_OFF + b] = fmaf(log2f(ee), LN2f, mm);
    } else if (wv == 2) {
        // ---------------- sequence score ----------------
        const int* lb = label + (size_t)b * Tn;
        float acc = 0.f;
        for (int t = lane; t < Tn; t += 64) {
            if (t < slen) {
                int lc = lb[t];
                acc += es[t * Ln + lc];
                if (t >= 1) acc += trans[lb[t - 1] * Ln + lc];
            }
        }
        #pragma unroll
        for (int off = 32; off >= 1; off >>= 1) acc += __shfl_xor(acc, off);
        if (lane == 0) wsf[SCORE_OFF + b] = acc;
    }
    __syncthreads();

    // ---------------- parallel backtrace ----------------
    int sseg = tid >> 5, ent = tid & 31;
    {
        int y = ent;
        for (int p = 32 * sseg + 31; p >= 32 * sseg; p--) y = bp[p * Ln + y];
        Fm[sseg * 32 + ent] = (uint8_t)y;
    }
    __syncthreads();
    if (tid == 0) {
        int y = s_last;
        btag[15] = y;
        for (int ss = 15; ss >= 1; ss--) { y = Fm[ss * 32 + y]; btag[ss - 1] = y; }
    }
    __syncthreads();
    int q = tid;
    int y = btag[sseg];
    for (int p = 32 * sseg + 31; p >= q + 1; p--) y = bp[p * Ln + y];
    out[1 + (size_t)b * Tn + q] = (float)y;

    int lbl = label[(size_t)b * Tn + q];
    float tpf = (lbl > 0 && y == lbl) ? 1.f : 0.f;
    float tnf = (lbl > 0 && y != lbl) ? 1.f : 0.f;
    float fpf = (q < slen && lbl == 0 && y > 0) ? 1.f : 0.f;
    #pragma unroll
    for (int off = 32; off >= 1; off >>= 1) {
        tpf += __shfl_xor(tpf, off);
        tnf += __shfl_xor(tnf, off);
        fpf += __shfl_xor(fpf, off);
    }
    if (lane == 0) { credA[wv] = tpf; credB[wv] = tnf; credC[wv] = fpf; }
    __syncthreads();
    if (tid == 0) {
        float a = 0.f, bb2 = 0.f, c = 0.f;
        #pragma unroll
        for (int w = 0; w < 8; w++) { a += credA[w]; bb2 += credB[w]; c += credC[w]; }
        wsf[CNT_OFF + b] = a;
        wsf[CNT_OFF + Bn + b] = bb2;
        wsf[CNT_OFF + 2 * Bn + b] = c;
    }
}

// ---------------------------------------------------------------------------
// Kernel 3: final scalar reductions
// ---------------------------------------------------------------------------
__global__ __launch_bounds__(64) void crf_final(const float* __restrict__ wsf,
                                                float* __restrict__ out)
{
    int lane = threadIdx.x;
    float nll = wsf[LOGNORM_OFF + lane] - wsf[SCORE_OFF + lane];
    float tp = wsf[CNT_OFF + lane];
    float tn = wsf[CNT_OFF + Bn + lane];
    float fp = wsf[CNT_OFF + 2 * Bn + lane];
    #pragma unroll
    for (int off = 32; off >= 1; off >>= 1) {
        nll += __shfl_xor(nll, off);
        tp  += __shfl_xor(tp, off);
        tn  += __shfl_xor(tn, off);
        fp  += __shfl_xor(fp, off);
    }
    if (lane == 0) {
        out[0] = nll * (1.f / 64.f);
        out[1 + Bn * Tn + 0] = tp;
        out[1 + Bn * Tn + 1] = tn;
        out[1 + Bn * Tn + 2] = fp;
    }
}

extern "C" void kernel_launch(void* const* d_in, const int* in_sizes, int n_in,
                              void* d_out, int out_size, void* d_ws, size_t ws_size,
                              hipStream_t stream) {
    const float* x     = (const float*)d_in[0];
    const float* W     = (const float*)d_in[1];
    const float* bias  = (const float*)d_in[2];
    const float* trans = (const float*)d_in[3];
    const int* label   = (const int*)d_in[4];
    const int* seqlen  = (const int*)d_in[5];
    float* out = (float*)d_out;
    float* wsf = (float*)d_ws;

    gemm_emis<<<dim3(Bn * (Tn / BM)), dim3(256), 0, stream>>>(x, W, bias, seqlen, wsf + EMIS_OFF);
    crf_forward<<<dim3(Bn), dim3(512), 0, stream>>>(wsf + EMIS_OFF, trans, label, seqlen, out, wsf);
    crf_final<<<dim3(1), dim3(64), 0, stream>>>(wsf, out);
}

// Round 4
// 353.813 us; speedup vs baseline: 1.3314x; 1.0130x over previous
//
#include <hip/hip_runtime.h>
#include <stdint.h>

#define Bn 64
#define Tn 512
#define Dn 1024
#define Ln 32
#define LOG2E 1.4426950408889634f
#define LN2f  0.6931471805599453f

// workspace float offsets
#define EMIS_OFF 0
#define LOGNORM_OFF (Bn * Tn * Ln)          // 1048576
#define SCORE_OFF (LOGNORM_OFF + Bn)
#define CNT_OFF (SCORE_OFF + Bn)            // 3*Bn floats (tp, tn, fp per batch)

#define DO32(F) F(0) F(1) F(2) F(3) F(4) F(5) F(6) F(7) \
                F(8) F(9) F(10) F(11) F(12) F(13) F(14) F(15) \
                F(16) F(17) F(18) F(19) F(20) F(21) F(22) F(23) \
                F(24) F(25) F(26) F(27) F(28) F(29) F(30) F(31)

// ---------------------------------------------------------------------------
// Kernel 1: emissions = x @ W + bias. 256 blocks x 512 threads (2 waves/SIMD),
// register-prefetch pipeline: chunk k+1 global loads issue before compute of k.
// Skips 128-row tiles entirely past seqlen.
// ---------------------------------------------------------------------------
#define BM 128
#define KB 32
#define XSS 132   // mod 32 == 4: 4-way write conflict only; b128-read aligned

__global__ __launch_bounds__(512) void gemm_emis(
    const float* __restrict__ x, const float* __restrict__ Wm,
    const float* __restrict__ bias, const int* __restrict__ seqlen,
    float* __restrict__ emis)
{
    int b  = blockIdx.x >> 2;
    int t0 = (blockIdx.x & 3) * BM;
    if (t0 >= seqlen[b]) return;

    __shared__ __align__(16) float xs[KB * XSS];   // transposed: xs[k][row]
    __shared__ __align__(16) float wsh[KB * Ln];   // wsh[k][col]

    int tid = threadIdx.x;
    int cg = tid & 15;      // cols 2cg..2cg+1
    int rr = tid >> 4;      // rows 4rr..4rr+3

    const float* xrow = x + (size_t)(b * Tn + t0) * Dn;

    // x-staging indices: thread loads float4s #tid and #tid+512 of the chunk
    int lr0 = tid >> 3,        kk0 = tid & 7;
    int lr1 = (tid + 512) >> 3, kk1 = tid & 7;   // (tid+512)&7 == tid&7

    float acc[4][2];
    #pragma unroll
    for (int z = 0; z < 4; z++) { acc[z][0] = 0.f; acc[z][1] = 0.f; }

    // prologue: prefetch chunk 0
    float4 xr0 = *(const float4*)(xrow + (size_t)lr0 * Dn + kk0 * 4);
    float4 xr1 = *(const float4*)(xrow + (size_t)lr1 * Dn + kk1 * 4);
    float4 wr;
    if (tid < 256) wr = *(const float4*)(Wm + tid * 4);

    for (int k0 = 0; k0 < Dn; k0 += KB) {
        __syncthreads();   // previous chunk's compute done
        xs[(4 * kk0 + 0) * XSS + lr0] = xr0.x;
        xs[(4 * kk0 + 1) * XSS + lr0] = xr0.y;
        xs[(4 * kk0 + 2) * XSS + lr0] = xr0.z;
        xs[(4 * kk0 + 3) * XSS + lr0] = xr0.w;
        xs[(4 * kk1 + 0) * XSS + lr1] = xr1.x;
        xs[(4 * kk1 + 1) * XSS + lr1] = xr1.y;
        xs[(4 * kk1 + 2) * XSS + lr1] = xr1.z;
        xs[(4 * kk1 + 3) * XSS + lr1] = xr1.w;
        if (tid < 256) *(float4*)(wsh + tid * 4) = wr;
        __syncthreads();

        int kn = k0 + KB;
        if (kn < Dn) {   // prefetch next chunk (loads in flight during compute)
            xr0 = *(const float4*)(xrow + (size_t)lr0 * Dn + kn + kk0 * 4);
            xr1 = *(const float4*)(xrow + (size_t)lr1 * Dn + kn + kk1 * 4);
            if (tid < 256) wr = *(const float4*)(Wm + (size_t)kn * Ln + tid * 4);
        }

        #pragma unroll 8
        for (int k = 0; k < KB; k++) {
            float4 a = *(const float4*)(xs + k * XSS + 4 * rr);
            float2 w = *(const float2*)(wsh + k * Ln + 2 * cg);
            float av[4] = {a.x, a.y, a.z, a.w};
            #pragma unroll
            for (int z = 0; z < 4; z++) {
                acc[z][0] = fmaf(av[z], w.x, acc[z][0]);
                acc[z][1] = fmaf(av[z], w.y, acc[z][1]);
            }
        }
    }

    float2 bv = *(const float2*)(bias + 2 * cg);
    #pragma unroll
    for (int z = 0; z < 4; z++) {
        float2 o;
        o.x = acc[z][0] + bv.x;
        o.y = acc[z][1] + bv.y;
        *(float2*)(emis + (size_t)(b * Tn + t0 + 4 * rr + z) * Ln + 2 * cg) = o;
    }
}

// ---------------------------------------------------------------------------
// Kernel 2: per-batch CRF. grid 64 x 512.
// wave0 = Viterbi forward (max-only; alphas -> LDS), wave1 = log-norm,
// wave2 = seq score. Then ALL waves recompute backpointers in parallel over t
// (first-index argmax, identical semantics, off the serial critical path),
// then segmented parallel backtrace.
// ---------------------------------------------------------------------------
__global__ __launch_bounds__(512) void crf_forward(
    const float* __restrict__ emis, const float* __restrict__ trans,
    const int* __restrict__ label, const int* __restrict__ seqlen,
    float* __restrict__ out, float* __restrict__ wsf)
{
    __shared__ __align__(16) float es[Tn * Ln];   // 64 KB emissions
    __shared__ __align__(16) float al[Tn * Ln];   // 64 KB alpha rows
    __shared__ __align__(16) float trs[Ln * Ln];  // 4 KB transitions
    __shared__ uint8_t bp[Tn * Ln];               // 16 KB backpointers
    __shared__ uint8_t Fm[16 * 32];
    __shared__ int btag[16];
    __shared__ int s_last;
    __shared__ float credA[8], credB[8], credC[8];

    int tid = threadIdx.x;
    int b = blockIdx.x;
    int slen = seqlen[b];
    int wv = tid >> 6;
    int lane = tid & 63;

    const float* eb = emis + (size_t)b * Tn * Ln;

    // stage emissions (rows < slen), transitions; init bp identity
    {
        int n4 = slen * (Ln / 4);
        for (int i4 = tid; i4 < n4; i4 += 512)
            ((float4*)es)[i4] = ((const float4*)eb)[i4];
    }
    if (tid < 256) ((float4*)trs)[tid] = ((const float4*)trans)[tid];
    {
        uint32_t* bp32 = (uint32_t*)bp;
        for (int w = tid; w < Tn * Ln / 4; w += 512)
            bp32[w] = 0x03020100u + 0x04040404u * (uint32_t)(w & 7);
    }
    __syncthreads();

    if (wv == 0) {
        // ---------------- Viterbi forward: max only, alphas to LDS ---------
        int j = lane & 31;
        float tr[32];
        #pragma unroll
        for (int i = 0; i < 32; i++) tr[i] = trs[i * Ln + j];

        float av = es[j];
        if (lane < 32) al[j] = av;
        float emit = es[Ln + j];   // t=1 preload

        for (int t = 1; t < slen; t++) {
            int tnx = (t + 1 < slen) ? (t + 1) : (slen - 1);
            float emitn = es[tnx * Ln + j];

            int avi = __float_as_int(av);
            float vv[32];
            #define VSTEP(i) vv[i] = __int_as_float(__builtin_amdgcn_readlane(avi, i)) + tr[i];
            DO32(VSTEP)
            #undef VSTEP
            // pure max tree (fuses to v_max3_f32); exact, order-independent
            float u[11];
            #pragma unroll
            for (int g = 0; g < 10; g++)
                u[g] = fmaxf(fmaxf(vv[3 * g], vv[3 * g + 1]), vv[3 * g + 2]);
            u[10] = fmaxf(vv[30], vv[31]);
            float w0 = fmaxf(fmaxf(u[0], u[1]), u[2]);
            float w1 = fmaxf(fmaxf(u[3], u[4]), u[5]);
            float w2 = fmaxf(fmaxf(u[6], u[7]), u[8]);
            float w3 = fmaxf(u[9], u[10]);
            av = fmaxf(fmaxf(w0, w1), fmaxf(w2, w3)) + emit;
            if (lane < 32) al[t * Ln + j] = av;
            emit = emitn;
        }
        // last = argmax(alpha), first-index ties
        float mm = av; int ai = j;
        #pragma unroll
        for (int off = 16; off >= 1; off >>= 1) {
            float om = __shfl_xor(mm, off);
            int   oi = __shfl_xor(ai, off);
            if (om > mm || (om == mm && oi < ai)) { mm = om; ai = oi; }
        }
        if (lane == 0) s_last = ai;
    } else if (wv == 1) {
        // ---------------- log-norm forward (LSE, readlane broadcasts) ------
        int j = lane & 31;
        float e2[32];
        #pragma unroll
        for (int i = 0; i < 32; i++)
            e2[i] = exp2f(trs[i * Ln + j] * LOG2E);   // exp(T_ij)

        float alv = es[j];
        float emit = es[Ln + j];

        for (int t = 1; t < slen; t++) {
            int tnx = (t + 1 < slen) ? (t + 1) : (slen - 1);
            float emitn = es[tnx * Ln + j];

            float M = __int_as_float(__builtin_amdgcn_readfirstlane(__float_as_int(alv)));
            float w = exp2f((alv - M) * LOG2E);
            int wi = __float_as_int(w);
            float s0 = 0.f, s1 = 0.f, s2 = 0.f, s3 = 0.f;
            #define LSTEP(i) { float wb = __int_as_float(__builtin_amdgcn_readlane(wi, i)); \
                               if ((i & 3) == 0) s0 = fmaf(wb, e2[i], s0); \
                               else if ((i & 3) == 1) s1 = fmaf(wb, e2[i], s1); \
                               else if ((i & 3) == 2) s2 = fmaf(wb, e2[i], s2); \
                               else s3 = fmaf(wb, e2[i], s3); }
            DO32(LSTEP)
            #undef LSTEP
            float s = (s0 + s1) + (s2 + s3);
            alv = fmaf(log2f(s), LN2f, M) + emit;
            emit = emitn;
        }
        float mm = alv;
        #pragma unroll
        for (int off = 16; off >= 1; off >>= 1) mm = fmaxf(mm, __shfl_xor(mm, off));
        float ee = exp2f((alv - mm) * LOG2E);
        #pragma unroll
        for (int off = 16; off >= 1; off >>= 1) ee += __shfl_xor(ee, off);
        if (lane == 0) wsf[LOGNORM_OFF + b] = fmaf(log2f(ee), LN2f, mm);
    } else if (wv == 2) {
        // ---------------- sequence score ----------------
        const int* lb = label + (size_t)b * Tn;
        float acc = 0.f;
        for (int t = lane; t < Tn; t += 64) {
            if (t < slen) {
                int lc = lb[t];
                acc += es[t * Ln + lc];
                if (t >= 1) acc += trs[lb[t - 1] * Ln + lc];
            }
        }
        #pragma unroll
        for (int off = 32; off >= 1; off >>= 1) acc += __shfl_xor(acc, off);
        if (lane == 0) wsf[SCORE_OFF + b] = acc;
    }
    __syncthreads();

    // ------------- parallel backpointer recompute (all 512 threads) --------
    {
        int j = tid & 31, stripe = tid >> 5;   // 16 t-stripes
        float tr[32];
        #pragma unroll
        for (int i = 0; i < 32; i++) tr[i] = trs[i * Ln + j];
        for (int t = 1 + stripe; t < slen; t += 16) {
            const float* ar = al + (t - 1) * Ln;   // broadcast LDS reads
            float vv[32];
            #pragma unroll
            for (int i = 0; i < 32; i += 4) {
                float4 a4 = *(const float4*)(ar + i);
                vv[i]     = a4.x + tr[i];
                vv[i + 1] = a4.y + tr[i + 1];
                vv[i + 2] = a4.z + tr[i + 2];
                vv[i + 3] = a4.w + tr[i + 3];
            }
            // exact first-index argmax tree (pairs ascend; strict > keeps lo)
            float mv[16]; int mi[16];
            #pragma unroll
            for (int i = 0; i < 16; i++) {
                bool g = vv[2 * i + 1] > vv[2 * i];
                mv[i] = g ? vv[2 * i + 1] : vv[2 * i];
                mi[i] = g ? (2 * i + 1) : (2 * i);
            }
            #pragma unroll
            for (int i = 0; i < 8; i++) {
                bool g = mv[2 * i + 1] > mv[2 * i];
                mv[i] = g ? mv[2 * i + 1] : mv[2 * i];
                mi[i] = g ? mi[2 * i + 1] : mi[2 * i];
            }
            #pragma unroll
            for (int i = 0; i < 4; i++) {
                bool g = mv[2 * i + 1] > mv[2 * i];
                mv[i] = g ? mv[2 * i + 1] : mv[2 * i];
                mi[i] = g ? mi[2 * i + 1] : mi[2 * i];
            }
            #pragma unroll
            for (int i = 0; i < 2; i++) {
                bool g = mv[2 * i + 1] > mv[2 * i];
                mv[i] = g ? mv[2 * i + 1] : mv[2 * i];
                mi[i] = g ? mi[2 * i + 1] : mi[2 * i];
            }
            bp[t * Ln + j] = (uint8_t)mi[0];
        }
    }
    __syncthreads();

    // ---------------- segmented parallel backtrace ----------------
    int sseg = tid >> 5, ent = tid & 31;
    {
        int y = ent;
        for (int p = 32 * sseg + 31; p >= 32 * sseg; p--) y = bp[p * Ln + y];
        Fm[sseg * 32 + ent] = (uint8_t)y;
    }
    __syncthreads();
    if (tid == 0) {
        int y = s_last;
        btag[15] = y;
        for (int ss = 15; ss >= 1; ss--) { y = Fm[ss * 32 + y]; btag[ss - 1] = y; }
    }
    __syncthreads();
    int q = tid;
    int y = btag[sseg];
    for (int p = 32 * sseg + 31; p >= q + 1; p--) y = bp[p * Ln + y];
    out[1 + (size_t)b * Tn + q] = (float)y;

    int lbl = label[(size_t)b * Tn + q];
    float tpf = (lbl > 0 && y == lbl) ? 1.f : 0.f;
    float tnf = (lbl > 0 && y != lbl) ? 1.f : 0.f;
    float fpf = (q < slen && lbl == 0 && y > 0) ? 1.f : 0.f;
    #pragma unroll
    for (int off = 32; off >= 1; off >>= 1) {
        tpf += __shfl_xor(tpf, off);
        tnf += __shfl_xor(tnf, off);
        fpf += __shfl_xor(fpf, off);
    }
    if (lane == 0) { credA[wv] = tpf; credB[wv] = tnf; credC[wv] = fpf; }
    __syncthreads();
    if (tid == 0) {
        float a = 0.f, bb2 = 0.f, c = 0.f;
        #pragma unroll
        for (int w = 0; w < 8; w++) { a += credA[w]; bb2 += credB[w]; c += credC[w]; }
        wsf[CNT_OFF + b] = a;
        wsf[CNT_OFF + Bn + b] = bb2;
        wsf[CNT_OFF + 2 * Bn + b] = c;
    }
}

// ---------------------------------------------------------------------------
// Kernel 3: final scalar reductions
// ---------------------------------------------------------------------------
__global__ __launch_bounds__(64) void crf_final(const float* __restrict__ wsf,
                                                float* __restrict__ out)
{
    int lane = threadIdx.x;
    float nll = wsf[LOGNORM_OFF + lane] - wsf[SCORE_OFF + lane];
    float tp = wsf[CNT_OFF + lane];
    float tn = wsf[CNT_OFF + Bn + lane];
    float fp = wsf[CNT_OFF + 2 * Bn + lane];
    #pragma unroll
    for (int off = 32; off >= 1; off >>= 1) {
        nll += __shfl_xor(nll, off);
        tp  += __shfl_xor(tp, off);
        tn  += __shfl_xor(tn, off);
        fp  += __shfl_xor(fp, off);
    }
    if (lane == 0) {
        out[0] = nll * (1.f / 64.f);
        out[1 + Bn * Tn + 0] = tp;
        out[1 + Bn * Tn + 1] = tn;
        out[1 + Bn * Tn + 2] = fp;
    }
}

extern "C" void kernel_launch(void* const* d_in, const int* in_sizes, int n_in,
                              void* d_out, int out_size, void* d_ws, size_t ws_size,
                              hipStream_t stream) {
    const float* x     = (const float*)d_in[0];
    const float* W     = (const float*)d_in[1];
    const float* bias  = (const float*)d_in[2];
    const float* trans = (const float*)d_in[3];
    const int* label   = (const int*)d_in[4];
    const int* seqlen  = (const int*)d_in[5];
    float* out = (float*)d_out;
    float* wsf = (float*)d_ws;

    gemm_emis<<<dim3(Bn * (Tn / BM)), dim3(512), 0, stream>>>(x, W, bias, seqlen, wsf + EMIS_OFF);
    crf_forward<<<dim3(Bn), dim3(512), 0, stream>>>(wsf + EMIS_OFF, trans, label, seqlen, out, wsf);
    crf_final<<<dim3(1), dim3(64), 0, stream>>>(wsf, out);
}

// Round 5
// 352.833 us; speedup vs baseline: 1.3351x; 1.0028x over previous
//
#include <hip/hip_runtime.h>
#include <stdint.h>
#include <math.h>

#define Bn 64
#define Tn 512
#define Dn 1024
#define Ln 32
#define LOG2E 1.4426950408889634f
#define LN2f  0.6931471805599453f

// workspace float offsets
#define EMIS_OFF 0
#define LOGNORM_OFF (Bn * Tn * Ln)          // 1048576
#define SCORE_OFF (LOGNORM_OFF + Bn)
#define CNT_OFF (SCORE_OFF + Bn)            // 3*Bn floats (tp, tn, fp per batch)

#define DO32(F) F(0) F(1) F(2) F(3) F(4) F(5) F(6) F(7) \
                F(8) F(9) F(10) F(11) F(12) F(13) F(14) F(15) \
                F(16) F(17) F(18) F(19) F(20) F(21) F(22) F(23) \
                F(24) F(25) F(26) F(27) F(28) F(29) F(30) F(31)

// ---------------------------------------------------------------------------
// Kernel 1: emissions = x @ W + bias (unchanged from R4 — saved ~35 µs there)
// ---------------------------------------------------------------------------
#define BM 128
#define KB 32
#define XSS 132

__global__ __launch_bounds__(512) void gemm_emis(
    const float* __restrict__ x, const float* __restrict__ Wm,
    const float* __restrict__ bias, const int* __restrict__ seqlen,
    float* __restrict__ emis)
{
    int b  = blockIdx.x >> 2;
    int t0 = (blockIdx.x & 3) * BM;
    if (t0 >= seqlen[b]) return;

    __shared__ __align__(16) float xs[KB * XSS];
    __shared__ __align__(16) float wsh[KB * Ln];

    int tid = threadIdx.x;
    int cg = tid & 15;
    int rr = tid >> 4;

    const float* xrow = x + (size_t)(b * Tn + t0) * Dn;

    int lr0 = tid >> 3,         kk0 = tid & 7;
    int lr1 = (tid + 512) >> 3, kk1 = tid & 7;

    float acc[4][2];
    #pragma unroll
    for (int z = 0; z < 4; z++) { acc[z][0] = 0.f; acc[z][1] = 0.f; }

    float4 xr0 = *(const float4*)(xrow + (size_t)lr0 * Dn + kk0 * 4);
    float4 xr1 = *(const float4*)(xrow + (size_t)lr1 * Dn + kk1 * 4);
    float4 wr;
    if (tid < 256) wr = *(const float4*)(Wm + tid * 4);

    for (int k0 = 0; k0 < Dn; k0 += KB) {
        __syncthreads();
        xs[(4 * kk0 + 0) * XSS + lr0] = xr0.x;
        xs[(4 * kk0 + 1) * XSS + lr0] = xr0.y;
        xs[(4 * kk0 + 2) * XSS + lr0] = xr0.z;
        xs[(4 * kk0 + 3) * XSS + lr0] = xr0.w;
        xs[(4 * kk1 + 0) * XSS + lr1] = xr1.x;
        xs[(4 * kk1 + 1) * XSS + lr1] = xr1.y;
        xs[(4 * kk1 + 2) * XSS + lr1] = xr1.z;
        xs[(4 * kk1 + 3) * XSS + lr1] = xr1.w;
        if (tid < 256) *(float4*)(wsh + tid * 4) = wr;
        __syncthreads();

        int kn = k0 + KB;
        if (kn < Dn) {
            xr0 = *(const float4*)(xrow + (size_t)lr0 * Dn + kn + kk0 * 4);
            xr1 = *(const float4*)(xrow + (size_t)lr1 * Dn + kn + kk1 * 4);
            if (tid < 256) wr = *(const float4*)(Wm + (size_t)kn * Ln + tid * 4);
        }

        #pragma unroll 8
        for (int k = 0; k < KB; k++) {
            float4 a = *(const float4*)(xs + k * XSS + 4 * rr);
            float2 w = *(const float2*)(wsh + k * Ln + 2 * cg);
            float av[4] = {a.x, a.y, a.z, a.w};
            #pragma unroll
            for (int z = 0; z < 4; z++) {
                acc[z][0] = fmaf(av[z], w.x, acc[z][0]);
                acc[z][1] = fmaf(av[z], w.y, acc[z][1]);
            }
        }
    }

    float2 bv = *(const float2*)(bias + 2 * cg);
    #pragma unroll
    for (int z = 0; z < 4; z++) {
        float2 o;
        o.x = acc[z][0] + bv.x;
        o.y = acc[z][1] + bv.y;
        *(float2*)(emis + (size_t)(b * Tn + t0 + 4 * rr + z) * Ln + 2 * cg) = o;
    }
}

// ---------------------------------------------------------------------------
// Kernel 2: per-batch CRF. grid 64 x 512. Chunked pipeline (CH=64):
//   wave0 = Viterbi forward (max-only, alphas->LDS)
//   wave1 = log-norm in SHIFTED-LINEAR space (no transcendental in chain)
//   waves2-7 = seq-score (chunk 0) then backpointer recompute for chunk c-1
// Then segmented parallel backtrace.
// ---------------------------------------------------------------------------
#define CH 64

__global__ __launch_bounds__(512) void crf_forward(
    const float* __restrict__ emis, const float* __restrict__ trans,
    const int* __restrict__ label, const int* __restrict__ seqlen,
    float* __restrict__ out, float* __restrict__ wsf)
{
    __shared__ __align__(16) float es[Tn * Ln];   // 64 KB emissions
    __shared__ __align__(16) float al[Tn * Ln];   // 64 KB alphas (post-emission)
    __shared__ __align__(16) float trs[Ln * Ln];  // 4 KB transitions
    __shared__ uint8_t bp[Tn * Ln];               // 16 KB backpointers
    __shared__ uint8_t Fm[16 * 32];
    __shared__ int btag[16];
    __shared__ int s_last;
    __shared__ float credA[8], credB[8], credC[8];

    int tid = threadIdx.x;
    int b = blockIdx.x;
    int slen = seqlen[b];
    int wv = tid >> 6;
    int lane = tid & 63;
    int j = lane & 31;

    const float* eb = emis + (size_t)b * Tn * Ln;

    {
        int n4 = slen * (Ln / 4);
        for (int i4 = tid; i4 < n4; i4 += 512)
            ((float4*)es)[i4] = ((const float4*)eb)[i4];
    }
    if (tid < 256) ((float4*)trs)[tid] = ((const float4*)trans)[tid];
    {
        uint32_t* bp32 = (uint32_t*)bp;
        for (int w = tid; w < Tn * Ln / 4; w += 512)
            bp32[w] = 0x03020100u + 0x04040404u * (uint32_t)(w & 7);
    }
    __syncthreads();

    // per-role persistent state
    float av = 0.f, emit = 0.f;            // viterbi
    float a = 0.f, eemit = 0.f;            // LSE (shifted-linear)
    int   Eacc = 0;
    float tr[32];                          // wave0 & helpers: T[i][j]
    float e2[32];                          // wave1: exp(T[i][j])

    if (wv == 0) {
        #pragma unroll
        for (int i = 0; i < 32; i++) tr[i] = trs[i * Ln + j];
        av = es[j];
        if (lane < 32) al[j] = av;
        emit = es[Ln + j];
    } else if (wv == 1) {
        #pragma unroll
        for (int i = 0; i < 32; i++) e2[i] = exp2f(trs[i * Ln + j] * LOG2E);
        a = exp2f(es[j] * LOG2E);                 // a = exp(alpha0), Eacc = 0
        eemit = exp2f(es[Ln + j] * LOG2E);        // exp(emit_1) preloaded
    } else {
        #pragma unroll
        for (int i = 0; i < 32; i++) tr[i] = trs[i * Ln + j];
    }

    for (int c = 0; c < Tn / CH; c++) {
        int tb = (c == 0) ? 1 : c * CH;
        int te = (c + 1) * CH; if (te > slen) te = slen;

        if (wv == 0) {
            // ---------- Viterbi chunk: max only ----------
            for (int t = tb; t < te; t++) {
                int tnx = (t + 1 < slen) ? (t + 1) : (slen - 1);
                float emitn = es[tnx * Ln + j];

                int avi = __float_as_int(av);
                float vv[32];
                #define VSTEP(i) vv[i] = __int_as_float(__builtin_amdgcn_readlane(avi, i)) + tr[i];
                DO32(VSTEP)
                #undef VSTEP
                float u[11];
                #pragma unroll
                for (int g = 0; g < 10; g++)
                    u[g] = fmaxf(fmaxf(vv[3 * g], vv[3 * g + 1]), vv[3 * g + 2]);
                u[10] = fmaxf(vv[30], vv[31]);
                float w0 = fmaxf(fmaxf(u[0], u[1]), u[2]);
                float w1 = fmaxf(fmaxf(u[3], u[4]), u[5]);
                float w2 = fmaxf(fmaxf(u[6], u[7]), u[8]);
                float w3 = fmaxf(u[9], u[10]);
                av = fmaxf(fmaxf(w0, w1), fmaxf(w2, w3)) + emit;
                if (lane < 32) al[t * Ln + j] = av;
                emit = emitn;
            }
        } else if (wv == 1) {
            // ---------- LSE chunk: shifted-linear, pow2 renorm ----------
            for (int t = tb; t < te; t++) {
                int tnx = (t + 1 < slen) ? (t + 1) : (slen - 1);
                float emitn = es[tnx * Ln + j];
                float eemitn = exp2f(emitn * LOG2E);   // off-chain, for t+1

                int ai = __float_as_int(a);
                float s0 = 0.f, s1 = 0.f, s2 = 0.f, s3 = 0.f;
                #define LSTEP(i) { float wb = __int_as_float(__builtin_amdgcn_readlane(ai, i)); \
                                   if ((i & 3) == 0) s0 = fmaf(wb, e2[i], s0); \
                                   else if ((i & 3) == 1) s1 = fmaf(wb, e2[i], s1); \
                                   else if ((i & 3) == 2) s2 = fmaf(wb, e2[i], s2); \
                                   else s3 = fmaf(wb, e2[i], s3); }
                DO32(LSTEP)
                #undef LSTEP
                float s = ((s0 + s1) + (s2 + s3)) * eemit;
                // renorm by 2^e where e = exponent of lane0's s (SALU, off-chain acc)
                unsigned sb = (unsigned)__builtin_amdgcn_readfirstlane(__float_as_int(s));
                int e = (int)((sb >> 23) & 0xFFu) - 127;
                Eacc += e;
                a = ldexpf(s, -e);
                eemit = eemitn;
            }
        } else if (c == 0) {
            if (wv == 2) {
                // ---------- sequence score (once) ----------
                const int* lb = label + (size_t)b * Tn;
                float acc = 0.f;
                for (int t = lane; t < Tn; t += 64) {
                    if (t < slen) {
                        int lc = lb[t];
                        acc += es[t * Ln + lc];
                        if (t >= 1) acc += trs[lb[t - 1] * Ln + lc];
                    }
                }
                #pragma unroll
                for (int off = 32; off >= 1; off >>= 1) acc += __shfl_xor(acc, off);
                if (lane == 0) wsf[SCORE_OFF + b] = acc;
            }
        } else {
            // ---------- bp recompute for chunk c-1 (12 stripes) ----------
            int stripe = (wv - 2) * 2 + (lane >> 5);   // 0..11
            int pb = ((c - 1) == 0) ? 1 : (c - 1) * CH;
            int pe = c * CH; if (pe > slen) pe = slen;
            for (int t = pb + stripe; t < pe; t += 12) {
                const float* ar = al + (t - 1) * Ln;
                float vv[32];
                #pragma unroll
                for (int i = 0; i < 32; i += 4) {
                    float4 a4 = *(const float4*)(ar + i);
                    vv[i]     = a4.x + tr[i];
                    vv[i + 1] = a4.y + tr[i + 1];
                    vv[i + 2] = a4.z + tr[i + 2];
                    vv[i + 3] = a4.w + tr[i + 3];
                }
                float mv[16]; int mi[16];
                #pragma unroll
                for (int i = 0; i < 16; i++) {
                    bool g = vv[2 * i + 1] > vv[2 * i];
                    mv[i] = g ? vv[2 * i + 1] : vv[2 * i];
                    mi[i] = g ? (2 * i + 1) : (2 * i);
                }
                #pragma unroll
                for (int i = 0; i < 8; i++) {
                    bool g = mv[2 * i + 1] > mv[2 * i];
                    mv[i] = g ? mv[2 * i + 1] : mv[2 * i];
                    mi[i] = g ? mi[2 * i + 1] : mi[2 * i];
                }
                #pragma unroll
                for (int i = 0; i < 4; i++) {
                    bool g = mv[2 * i + 1] > mv[2 * i];
                    mv[i] = g ? mv[2 * i + 1] : mv[2 * i];
                    mi[i] = g ? mi[2 * i + 1] : mi[2 * i];
                }
                #pragma unroll
                for (int i = 0; i < 2; i++) {
                    bool g = mv[2 * i + 1] > mv[2 * i];
                    mv[i] = g ? mv[2 * i + 1] : mv[2 * i];
                    mi[i] = g ? mi[2 * i + 1] : mi[2 * i];
                }
                bp[t * Ln + j] = (uint8_t)mi[0];
            }
        }
        __syncthreads();
    }

    // tail: finalize forwards; waves 2-7 do last chunk's backpointers
    if (wv == 0) {
        float mm = av; int ai = j;
        #pragma unroll
        for (int off = 16; off >= 1; off >>= 1) {
            float om = __shfl_xor(mm, off);
            int   oi = __shfl_xor(ai, off);
            if (om > mm || (om == mm && oi < ai)) { mm = om; ai = oi; }
        }
        if (lane == 0) s_last = ai;
    } else if (wv == 1) {
        // logZ = LN2*Eacc + ln(sum_j a_j)   (a_j > 0, halves duplicated)
        float ss = a;
        #pragma unroll
        for (int off = 16; off >= 1; off >>= 1) ss += __shfl_xor(ss, off);
        if (lane == 0)
            wsf[LOGNORM_OFF + b] = fmaf(log2f(ss) + (float)Eacc, LN2f, 0.f);
    } else {
        int stripe = (wv - 2) * 2 + (lane >> 5);
        int cc = Tn / CH - 1;
        int pb = cc * CH;
        int pe = Tn; if (pe > slen) pe = slen;
        for (int t = pb + stripe; t < pe; t += 12) {
            const float* ar = al + (t - 1) * Ln;
            float vv[32];
            #pragma unroll
            for (int i = 0; i < 32; i += 4) {
                float4 a4 = *(const float4*)(ar + i);
                vv[i]     = a4.x + tr[i];
                vv[i + 1] = a4.y + tr[i + 1];
                vv[i + 2] = a4.z + tr[i + 2];
                vv[i + 3] = a4.w + tr[i + 3];
            }
            float mv[16]; int mi[16];
            #pragma unroll
            for (int i = 0; i < 16; i++) {
                bool g = vv[2 * i + 1] > vv[2 * i];
                mv[i] = g ? vv[2 * i + 1] : vv[2 * i];
                mi[i] = g ? (2 * i + 1) : (2 * i);
            }
            #pragma unroll
            for (int i = 0; i < 8; i++) {
                bool g = mv[2 * i + 1] > mv[2 * i];
                mv[i] = g ? mv[2 * i + 1] : mv[2 * i];
                mi[i] = g ? mi[2 * i + 1] : mi[2 * i];
            }
            #pragma unroll
            for (int i = 0; i < 4; i++) {
                bool g = mv[2 * i + 1] > mv[2 * i];
                mv[i] = g ? mv[2 * i + 1] : mv[2 * i];
                mi[i] = g ? mi[2 * i + 1] : mi[2 * i];
            }
            #pragma unroll
            for (int i = 0; i < 2; i++) {
                bool g = mv[2 * i + 1] > mv[2 * i];
                mv[i] = g ? mv[2 * i + 1] : mv[2 * i];
                mi[i] = g ? mi[2 * i + 1] : mi[2 * i];
            }
            bp[t * Ln + j] = (uint8_t)mi[0];
        }
    }
    __syncthreads();

    // ---------------- segmented parallel backtrace ----------------
    int sseg = tid >> 5, ent = tid & 31;
    {
        int y = ent;
        for (int p = 32 * sseg + 31; p >= 32 * sseg; p--) y = bp[p * Ln + y];
        Fm[sseg * 32 + ent] = (uint8_t)y;
    }
    __syncthreads();
    if (tid == 0) {
        int y = s_last;
        btag[15] = y;
        for (int ss = 15; ss >= 1; ss--) { y = Fm[ss * 32 + y]; btag[ss - 1] = y; }
    }
    __syncthreads();
    int q = tid;
    int y = btag[sseg];
    for (int p = 32 * sseg + 31; p >= q + 1; p--) y = bp[p * Ln + y];
    out[1 + (size_t)b * Tn + q] = (float)y;

    int lbl = label[(size_t)b * Tn + q];
    float tpf = (lbl > 0 && y == lbl) ? 1.f : 0.f;
    float tnf = (lbl > 0 && y != lbl) ? 1.f : 0.f;
    float fpf = (q < slen && lbl == 0 && y > 0) ? 1.f : 0.f;
    #pragma unroll
    for (int off = 32; off >= 1; off >>= 1) {
        tpf += __shfl_xor(tpf, off);
        tnf += __shfl_xor(tnf, off);
        fpf += __shfl_xor(fpf, off);
    }
    if (lane == 0) { credA[wv] = tpf; credB[wv] = tnf; credC[wv] = fpf; }
    __syncthreads();
    if (tid == 0) {
        float aa = 0.f, bb2 = 0.f, cc2 = 0.f;
        #pragma unroll
        for (int w = 0; w < 8; w++) { aa += credA[w]; bb2 += credB[w]; cc2 += credC[w]; }
        wsf[CNT_OFF + b] = aa;
        wsf[CNT_OFF + Bn + b] = bb2;
        wsf[CNT_OFF + 2 * Bn + b] = cc2;
    }
}

// ---------------------------------------------------------------------------
// Kernel 3: final scalar reductions
// ---------------------------------------------------------------------------
__global__ __launch_bounds__(64) void crf_final(const float* __restrict__ wsf,
                                                float* __restrict__ out)
{
    int lane = threadIdx.x;
    float nll = wsf[LOGNORM_OFF + lane] - wsf[SCORE_OFF + lane];
    float tp = wsf[CNT_OFF + lane];
    float tn = wsf[CNT_OFF + Bn + lane];
    float fp = wsf[CNT_OFF + 2 * Bn + lane];
    #pragma unroll
    for (int off = 32; off >= 1; off >>= 1) {
        nll += __shfl_xor(nll, off);
        tp  += __shfl_xor(tp, off);
        tn  += __shfl_xor(tn, off);
        fp  += __shfl_xor(fp, off);
    }
    if (lane == 0) {
        out[0] = nll * (1.f / 64.f);
        out[1 + Bn * Tn + 0] = tp;
        out[1 + Bn * Tn + 1] = tn;
        out[1 + Bn * Tn + 2] = fp;
    }
}

extern "C" void kernel_launch(void* const* d_in, const int* in_sizes, int n_in,
                              void* d_out, int out_size, void* d_ws, size_t ws_size,
                              hipStream_t stream) {
    const float* x     = (const float*)d_in[0];
    const float* W     = (const float*)d_in[1];
    const float* bias  = (const float*)d_in[2];
    const float* trans = (const float*)d_in[3];
    const int* label   = (const int*)d_in[4];
    const int* seqlen  = (const int*)d_in[5];
    float* out = (float*)d_out;
    float* wsf = (float*)d_ws;

    gemm_emis<<<dim3(Bn * (Tn / BM)), dim3(512), 0, stream>>>(x, W, bias, seqlen, wsf + EMIS_OFF);
    crf_forward<<<dim3(Bn), dim3(512), 0, stream>>>(wsf + EMIS_OFF, trans, label, seqlen, out, wsf);
    crf_final<<<dim3(1), dim3(64), 0, stream>>>(wsf, out);
}

// Round 6
// 319.051 us; speedup vs baseline: 1.4765x; 1.1059x over previous
//
#include <hip/hip_runtime.h>
#include <stdint.h>
#include <math.h>

#define Bn 64
#define Tn 512
#define Dn 1024
#define Ln 32
#define LOG2E 1.4426950408889634f
#define LN2f  0.6931471805599453f

// workspace float offsets
#define EMIS_OFF 0
#define LOGNORM_OFF (Bn * Tn * Ln)
#define SCORE_OFF (LOGNORM_OFF + Bn)
#define CNT_OFF (SCORE_OFF + Bn)

// ---------------------------------------------------------------------------
// Kernel 1: emissions = x @ W + bias. 256 blocks x 256 threads.
// Thread tile 4x4: per k -> 2 ds_read_b128 per 16 fma (was 2 reads per 8 fma).
// Register-prefetch pipeline for global->LDS staging. Skips tiles past seqlen.
// ---------------------------------------------------------------------------
#define BM 128
#define KB 32
#define XSS 132

__global__ __launch_bounds__(256) void gemm_emis(
    const float* __restrict__ x, const float* __restrict__ Wm,
    const float* __restrict__ bias, const int* __restrict__ seqlen,
    float* __restrict__ emis)
{
    int b  = blockIdx.x >> 2;
    int t0 = (blockIdx.x & 3) * BM;
    if (t0 >= seqlen[b]) return;

    __shared__ __align__(16) float xs[KB * XSS];   // transposed: xs[k][row]
    __shared__ __align__(16) float wsh[KB * Ln];   // wsh[k][col]

    int tid = threadIdx.x;
    int cg = tid & 7;       // cols 4cg..4cg+3
    int rg = tid >> 3;      // rows 4rg..4rg+3 (0..31)

    const float* xrow = x + (size_t)(b * Tn + t0) * Dn;

    float acc[4][4];
    #pragma unroll
    for (int z = 0; z < 4; z++)
        #pragma unroll
        for (int c = 0; c < 4; c++) acc[z][c] = 0.f;

    // prologue: prefetch chunk 0 into registers
    float4 xr[4]; float4 wr;
    #pragma unroll
    for (int u = 0; u < 4; u++) {
        int f = tid + 256 * u;
        xr[u] = *(const float4*)(xrow + (size_t)(f >> 3) * Dn + (f & 7) * 4);
    }
    wr = *(const float4*)(Wm + tid * 4);

    for (int k0 = 0; k0 < Dn; k0 += KB) {
        __syncthreads();
        #pragma unroll
        for (int u = 0; u < 4; u++) {
            int f = tid + 256 * u;
            int lrow = f >> 3, kk = f & 7;
            xs[(4 * kk + 0) * XSS + lrow] = xr[u].x;
            xs[(4 * kk + 1) * XSS + lrow] = xr[u].y;
            xs[(4 * kk + 2) * XSS + lrow] = xr[u].z;
            xs[(4 * kk + 3) * XSS + lrow] = xr[u].w;
        }
        *(float4*)(wsh + tid * 4) = wr;
        __syncthreads();

        int kn = k0 + KB;
        if (kn < Dn) {
            #pragma unroll
            for (int u = 0; u < 4; u++) {
                int f = tid + 256 * u;
                xr[u] = *(const float4*)(xrow + (size_t)(f >> 3) * Dn + kn + (f & 7) * 4);
            }
            wr = *(const float4*)(Wm + (size_t)kn * Ln + tid * 4);
        }

        #pragma unroll 8
        for (int k = 0; k < KB; k++) {
            float4 a = *(const float4*)(xs + k * XSS + 4 * rg);
            float4 w = *(const float4*)(wsh + k * Ln + 4 * cg);
            float av[4] = {a.x, a.y, a.z, a.w};
            float wv[4] = {w.x, w.y, w.z, w.w};
            #pragma unroll
            for (int z = 0; z < 4; z++)
                #pragma unroll
                for (int c = 0; c < 4; c++)
                    acc[z][c] = fmaf(av[z], wv[c], acc[z][c]);
        }
    }

    float4 bv = *(const float4*)(bias + 4 * cg);
    float bb[4] = {bv.x, bv.y, bv.z, bv.w};
    #pragma unroll
    for (int z = 0; z < 4; z++) {
        float4 o;
        o.x = acc[z][0] + bb[0];
        o.y = acc[z][1] + bb[1];
        o.z = acc[z][2] + bb[2];
        o.w = acc[z][3] + bb[3];
        *(float4*)(emis + (size_t)(b * Tn + t0 + 4 * rg + z) * Ln + 4 * cg) = o;
    }
}

// ---------------------------------------------------------------------------
// Kernel 2: per-batch CRF. grid 64 x 512. Chunked pipeline (CH=64):
//   wave0 = Viterbi forward, wave1 = log-norm (shifted-linear, renorm every 4),
//   waves2-7 = seq-score (c=0) then bp recompute for chunk c-1.
// State broadcast: ONE LDS round trip per step (ds_write + 8x ds_read_b128
// broadcast) instead of 32 v_readlane (R3-R5 showed readlane-hazard ~550+
// cyc/step regardless of surrounding code).
// ---------------------------------------------------------------------------
#define CH 64

__global__ __launch_bounds__(512) void crf_forward(
    const float* __restrict__ emis, const float* __restrict__ trans,
    const int* __restrict__ label, const int* __restrict__ seqlen,
    float* __restrict__ out, float* __restrict__ wsf)
{
    __shared__ __align__(16) float es[Tn * Ln];   // 64 KB emissions
    __shared__ __align__(16) float al[Tn * Ln];   // 64 KB alphas
    __shared__ __align__(16) float trs[Ln * Ln];  // 4 KB transitions
    __shared__ __align__(16) float abuf[Ln];      // viterbi broadcast buffer
    __shared__ __align__(16) float lbuf[Ln];      // LSE broadcast buffer
    __shared__ uint8_t bp[Tn * Ln];               // 16 KB backpointers
    __shared__ uint8_t Fm[16 * 32];
    __shared__ int btag[16];
    __shared__ int s_last;
    __shared__ float credA[8], credB[8], credC[8];

    int tid = threadIdx.x;
    int b = blockIdx.x;
    int slen = seqlen[b];
    int wv = tid >> 6;
    int lane = tid & 63;
    int j = lane & 31;

    const float* eb = emis + (size_t)b * Tn * Ln;

    {
        int n4 = slen * (Ln / 4);
        for (int i4 = tid; i4 < n4; i4 += 512)
            ((float4*)es)[i4] = ((const float4*)eb)[i4];
    }
    if (tid < 256) ((float4*)trs)[tid] = ((const float4*)trans)[tid];
    {
        uint32_t* bp32 = (uint32_t*)bp;
        for (int w = tid; w < Tn * Ln / 4; w += 512)
            bp32[w] = 0x03020100u + 0x04040404u * (uint32_t)(w & 7);
    }
    __syncthreads();

    float av = 0.f, emit = 0.f;            // viterbi
    float a = 0.f, eemit = 0.f;            // LSE
    int   Eacc = 0;
    float tr[32];
    float e2[32];

    if (wv == 0) {
        #pragma unroll
        for (int i = 0; i < 32; i++) tr[i] = trs[i * Ln + j];
        av = es[j];
        if (lane < 32) al[j] = av;
        emit = es[Ln + j];
    } else if (wv == 1) {
        #pragma unroll
        for (int i = 0; i < 32; i++) e2[i] = exp2f(trs[i * Ln + j] * LOG2E);
        a = exp2f(es[j] * LOG2E);
        eemit = exp2f(es[Ln + j] * LOG2E);
    } else {
        #pragma unroll
        for (int i = 0; i < 32; i++) tr[i] = trs[i * Ln + j];
    }

    for (int c = 0; c < Tn / CH; c++) {
        int tb = (c == 0) ? 1 : c * CH;
        int te = (c + 1) * CH; if (te > slen) te = slen;

        if (wv == 0) {
            // ---------- Viterbi: LDS-broadcast + max3 tree ----------
            for (int t = tb; t < te; t++) {
                int tnx = (t + 1 < slen) ? (t + 1) : (slen - 1);
                if (lane < 32) abuf[j] = av;           // ds_write
                float emitn = es[tnx * Ln + j];        // independent ds_read
                float4 A0 = *(const float4*)(abuf + 0);
                float4 A1 = *(const float4*)(abuf + 4);
                float4 A2 = *(const float4*)(abuf + 8);
                float4 A3 = *(const float4*)(abuf + 12);
                float4 A4 = *(const float4*)(abuf + 16);
                float4 A5 = *(const float4*)(abuf + 20);
                float4 A6 = *(const float4*)(abuf + 24);
                float4 A7 = *(const float4*)(abuf + 28);
                float vv[32];
                vv[0]=A0.x+tr[0];   vv[1]=A0.y+tr[1];   vv[2]=A0.z+tr[2];   vv[3]=A0.w+tr[3];
                vv[4]=A1.x+tr[4];   vv[5]=A1.y+tr[5];   vv[6]=A1.z+tr[6];   vv[7]=A1.w+tr[7];
                vv[8]=A2.x+tr[8];   vv[9]=A2.y+tr[9];   vv[10]=A2.z+tr[10]; vv[11]=A2.w+tr[11];
                vv[12]=A3.x+tr[12]; vv[13]=A3.y+tr[13]; vv[14]=A3.z+tr[14]; vv[15]=A3.w+tr[15];
                vv[16]=A4.x+tr[16]; vv[17]=A4.y+tr[17]; vv[18]=A4.z+tr[18]; vv[19]=A4.w+tr[19];
                vv[20]=A5.x+tr[20]; vv[21]=A5.y+tr[21]; vv[22]=A5.z+tr[22]; vv[23]=A5.w+tr[23];
                vv[24]=A6.x+tr[24]; vv[25]=A6.y+tr[25]; vv[26]=A6.z+tr[26]; vv[27]=A6.w+tr[27];
                vv[28]=A7.x+tr[28]; vv[29]=A7.y+tr[29]; vv[30]=A7.z+tr[30]; vv[31]=A7.w+tr[31];
                float u[11];
                #pragma unroll
                for (int g = 0; g < 10; g++)
                    u[g] = fmaxf(fmaxf(vv[3*g], vv[3*g+1]), vv[3*g+2]);
                u[10] = fmaxf(vv[30], vv[31]);
                float w0 = fmaxf(fmaxf(u[0], u[1]), u[2]);
                float w1 = fmaxf(fmaxf(u[3], u[4]), u[5]);
                float w2 = fmaxf(fmaxf(u[6], u[7]), u[8]);
                float w3 = fmaxf(u[9], u[10]);
                av = fmaxf(fmaxf(w0, w1), fmaxf(w2, w3)) + emit;
                if (lane < 32) al[t * Ln + j] = av;
                emit = emitn;
            }
        } else if (wv == 1) {
            // ---------- LSE: LDS-broadcast, shifted-linear ----------
            for (int t = tb; t < te; t++) {
                int tnx = (t + 1 < slen) ? (t + 1) : (slen - 1);
                if (lane < 32) lbuf[j] = a;            // ds_write
                float emitn = es[tnx * Ln + j];
                float4 A0 = *(const float4*)(lbuf + 0);
                float4 A1 = *(const float4*)(lbuf + 4);
                float4 A2 = *(const float4*)(lbuf + 8);
                float4 A3 = *(const float4*)(lbuf + 12);
                float4 A4 = *(const float4*)(lbuf + 16);
                float4 A5 = *(const float4*)(lbuf + 20);
                float4 A6 = *(const float4*)(lbuf + 24);
                float4 A7 = *(const float4*)(lbuf + 28);
                float eemitn = exp2f(emitn * LOG2E);   // off-chain
                float s0, s1, s2, s3;
                s0 = A0.x * e2[0];  s1 = A0.y * e2[1];  s2 = A0.z * e2[2];  s3 = A0.w * e2[3];
                s0 = fmaf(A1.x, e2[4], s0);  s1 = fmaf(A1.y, e2[5], s1);
                s2 = fmaf(A1.z, e2[6], s2);  s3 = fmaf(A1.w, e2[7], s3);
                s0 = fmaf(A2.x, e2[8], s0);  s1 = fmaf(A2.y, e2[9], s1);
                s2 = fmaf(A2.z, e2[10], s2); s3 = fmaf(A2.w, e2[11], s3);
                s0 = fmaf(A3.x, e2[12], s0); s1 = fmaf(A3.y, e2[13], s1);
                s2 = fmaf(A3.z, e2[14], s2); s3 = fmaf(A3.w, e2[15], s3);
                s0 = fmaf(A4.x, e2[16], s0); s1 = fmaf(A4.y, e2[17], s1);
                s2 = fmaf(A4.z, e2[18], s2); s3 = fmaf(A4.w, e2[19], s3);
                s0 = fmaf(A5.x, e2[20], s0); s1 = fmaf(A5.y, e2[21], s1);
                s2 = fmaf(A5.z, e2[22], s2); s3 = fmaf(A5.w, e2[23], s3);
                s0 = fmaf(A6.x, e2[24], s0); s1 = fmaf(A6.y, e2[25], s1);
                s2 = fmaf(A6.z, e2[26], s2); s3 = fmaf(A6.w, e2[27], s3);
                s0 = fmaf(A7.x, e2[28], s0); s1 = fmaf(A7.y, e2[29], s1);
                s2 = fmaf(A7.z, e2[30], s2); s3 = fmaf(A7.w, e2[31], s3);
                float s = ((s0 + s1) + (s2 + s3)) * eemit;
                if ((t & 3) == 0) {   // pow2 renorm every 4 steps (range-safe)
                    unsigned sb = (unsigned)__builtin_amdgcn_readfirstlane(__float_as_int(s));
                    int e = (int)((sb >> 23) & 0xFFu) - 127;
                    Eacc += e;
                    a = ldexpf(s, -e);
                } else {
                    a = s;
                }
                eemit = eemitn;
            }
        } else if (c == 0) {
            if (wv == 2) {
                const int* lb = label + (size_t)b * Tn;
                float acc = 0.f;
                for (int t = lane; t < Tn; t += 64) {
                    if (t < slen) {
                        int lc = lb[t];
                        acc += es[t * Ln + lc];
                        if (t >= 1) acc += trs[lb[t - 1] * Ln + lc];
                    }
                }
                #pragma unroll
                for (int off = 32; off >= 1; off >>= 1) acc += __shfl_xor(acc, off);
                if (lane == 0) wsf[SCORE_OFF + b] = acc;
            }
        } else {
            // ---------- bp recompute for chunk c-1 (12 stripes) ----------
            int stripe = (wv - 2) * 2 + (lane >> 5);
            int pb = ((c - 1) == 0) ? 1 : (c - 1) * CH;
            int pe = c * CH; if (pe > slen) pe = slen;
            for (int t = pb + stripe; t < pe; t += 12) {
                const float* ar = al + (t - 1) * Ln;
                float vv[32];
                #pragma unroll
                for (int i = 0; i < 32; i += 4) {
                    float4 a4 = *(const float4*)(ar + i);
                    vv[i]     = a4.x + tr[i];
                    vv[i + 1] = a4.y + tr[i + 1];
                    vv[i + 2] = a4.z + tr[i + 2];
                    vv[i + 3] = a4.w + tr[i + 3];
                }
                float mv[16]; int mi[16];
                #pragma unroll
                for (int i = 0; i < 16; i++) {
                    bool g = vv[2*i+1] > vv[2*i];
                    mv[i] = g ? vv[2*i+1] : vv[2*i];
                    mi[i] = g ? (2*i+1) : (2*i);
                }
                #pragma unroll
                for (int i = 0; i < 8; i++) {
                    bool g = mv[2*i+1] > mv[2*i];
                    mv[i] = g ? mv[2*i+1] : mv[2*i];
                    mi[i] = g ? mi[2*i+1] : mi[2*i];
                }
                #pragma unroll
                for (int i = 0; i < 4; i++) {
                    bool g = mv[2*i+1] > mv[2*i];
                    mv[i] = g ? mv[2*i+1] : mv[2*i];
                    mi[i] = g ? mi[2*i+1] : mi[2*i];
                }
                #pragma unroll
                for (int i = 0; i < 2; i++) {
                    bool g = mv[2*i+1] > mv[2*i];
                    mv[i] = g ? mv[2*i+1] : mv[2*i];
                    mi[i] = g ? mi[2*i+1] : mi[2*i];
                }
                bp[t * Ln + j] = (uint8_t)mi[0];
            }
        }
        __syncthreads();
    }

    // tail
    if (wv == 0) {
        float mm = av; int ai = j;
        #pragma unroll
        for (int off = 16; off >= 1; off >>= 1) {
            float om = __shfl_xor(mm, off);
            int   oi = __shfl_xor(ai, off);
            if (om > mm || (om == mm && oi < ai)) { mm = om; ai = oi; }
        }
        if (lane == 0) s_last = ai;
    } else if (wv == 1) {
        float ss = a;
        #pragma unroll
        for (int off = 16; off >= 1; off >>= 1) ss += __shfl_xor(ss, off);
        if (lane == 0)
            wsf[LOGNORM_OFF + b] = fmaf(log2f(ss) + (float)Eacc, LN2f, 0.f);
    } else {
        int stripe = (wv - 2) * 2 + (lane >> 5);
        int cc = Tn / CH - 1;
        int pb = cc * CH;
        int pe = Tn; if (pe > slen) pe = slen;
        for (int t = pb + stripe; t < pe; t += 12) {
            const float* ar = al + (t - 1) * Ln;
            float vv[32];
            #pragma unroll
            for (int i = 0; i < 32; i += 4) {
                float4 a4 = *(const float4*)(ar + i);
                vv[i]     = a4.x + tr[i];
                vv[i + 1] = a4.y + tr[i + 1];
                vv[i + 2] = a4.z + tr[i + 2];
                vv[i + 3] = a4.w + tr[i + 3];
            }
            float mv[16]; int mi[16];
            #pragma unroll
            for (int i = 0; i < 16; i++) {
                bool g = vv[2*i+1] > vv[2*i];
                mv[i] = g ? vv[2*i+1] : vv[2*i];
                mi[i] = g ? (2*i+1) : (2*i);
            }
            #pragma unroll
            for (int i = 0; i < 8; i++) {
                bool g = mv[2*i+1] > mv[2*i];
                mv[i] = g ? mv[2*i+1] : mv[2*i];
                mi[i] = g ? mi[2*i+1] : mi[2*i];
            }
            #pragma unroll
            for (int i = 0; i < 4; i++) {
                bool g = mv[2*i+1] > mv[2*i];
                mv[i] = g ? mv[2*i+1] : mv[2*i];
                mi[i] = g ? mi[2*i+1] : mi[2*i];
            }
            #pragma unroll
            for (int i = 0; i < 2; i++) {
                bool g = mv[2*i+1] > mv[2*i];
                mv[i] = g ? mv[2*i+1] : mv[2*i];
                mi[i] = g ? mi[2*i+1] : mi[2*i];
            }
            bp[t * Ln + j] = (uint8_t)mi[0];
        }
    }
    __syncthreads();

    // ---------------- segmented parallel backtrace ----------------
    int sseg = tid >> 5, ent = tid & 31;
    {
        int y = ent;
        for (int p = 32 * sseg + 31; p >= 32 * sseg; p--) y = bp[p * Ln + y];
        Fm[sseg * 32 + ent] = (uint8_t)y;
    }
    __syncthreads();
    if (tid == 0) {
        int y = s_last;
        btag[15] = y;
        for (int ss = 15; ss >= 1; ss--) { y = Fm[ss * 32 + y]; btag[ss - 1] = y; }
    }
    __syncthreads();
    int q = tid;
    int y = btag[sseg];
    for (int p = 32 * sseg + 31; p >= q + 1; p--) y = bp[p * Ln + y];
    out[1 + (size_t)b * Tn + q] = (float)y;

    int lbl = label[(size_t)b * Tn + q];
    float tpf = (lbl > 0 && y == lbl) ? 1.f : 0.f;
    float tnf = (lbl > 0 && y != lbl) ? 1.f : 0.f;
    float fpf = (q < slen && lbl == 0 && y > 0) ? 1.f : 0.f;
    #pragma unroll
    for (int off = 32; off >= 1; off >>= 1) {
        tpf += __shfl_xor(tpf, off);
        tnf += __shfl_xor(tnf, off);
        fpf += __shfl_xor(fpf, off);
    }
    if (lane == 0) { credA[wv] = tpf; credB[wv] = tnf; credC[wv] = fpf; }
    __syncthreads();
    if (tid == 0) {
        float aa = 0.f, bb2 = 0.f, cc2 = 0.f;
        #pragma unroll
        for (int w = 0; w < 8; w++) { aa += credA[w]; bb2 += credB[w]; cc2 += credC[w]; }
        wsf[CNT_OFF + b] = aa;
        wsf[CNT_OFF + Bn + b] = bb2;
        wsf[CNT_OFF + 2 * Bn + b] = cc2;
    }
}

// ---------------------------------------------------------------------------
// Kernel 3: final scalar reductions
// ---------------------------------------------------------------------------
__global__ __launch_bounds__(64) void crf_final(const float* __restrict__ wsf,
                                                float* __restrict__ out)
{
    int lane = threadIdx.x;
    float nll = wsf[LOGNORM_OFF + lane] - wsf[SCORE_OFF + lane];
    float tp = wsf[CNT_OFF + lane];
    float tn = wsf[CNT_OFF + Bn + lane];
    float fp = wsf[CNT_OFF + 2 * Bn + lane];
    #pragma unroll
    for (int off = 32; off >= 1; off >>= 1) {
        nll += __shfl_xor(nll, off);
        tp  += __shfl_xor(tp, off);
        tn  += __shfl_xor(tn, off);
        fp  += __shfl_xor(fp, off);
    }
    if (lane == 0) {
        out[0] = nll * (1.f / 64.f);
        out[1 + Bn * Tn + 0] = tp;
        out[1 + Bn * Tn + 1] = tn;
        out[1 + Bn * Tn + 2] = fp;
    }
}

extern "C" void kernel_launch(void* const* d_in, const int* in_sizes, int n_in,
                              void* d_out, int out_size, void* d_ws, size_t ws_size,
                              hipStream_t stream) {
    const float* x     = (const float*)d_in[0];
    const float* W     = (const float*)d_in[1];
    const float* bias  = (const float*)d_in[2];
    const float* trans = (const float*)d_in[3];
    const int* label   = (const int*)d_in[4];
    const int* seqlen  = (const int*)d_in[5];
    float* out = (float*)d_out;
    float* wsf = (float*)d_ws;

    gemm_emis<<<dim3(Bn * (Tn / BM)), dim3(256), 0, stream>>>(x, W, bias, seqlen, wsf + EMIS_OFF);
    crf_forward<<<dim3(Bn), dim3(512), 0, stream>>>(wsf + EMIS_OFF, trans, label, seqlen, out, wsf);
    crf_final<<<dim3(1), dim3(64), 0, stream>>>(wsf, out);
}